// Round 6
// baseline (524.504 us; speedup 1.0000x reference)
//
#include <hip/hip_runtime.h>

#define D 64
#define KCODES 1024
#define PTS_PER_BLK 256
#define MTILES 16        // 16 points per M-tile x 16 tiles = 256 points/block
#define NT 4             // 4 N-tiles of 16 codes per wave = 64 codes/wave, 256/block
#define CODE_CHUNKS 4    // 4 blocks cover the 1024 codes for one point-tile
#define PTILES 512       // N / PTS_PER_BLK
#define WL_CAP 2048

typedef _Float16 f16x8 __attribute__((ext_vector_type(8)));
typedef float f32x4 __attribute__((ext_vector_type(4)));

static __device__ __forceinline__ unsigned short f2h(float f) {  // RNE fp32->fp16
  _Float16 h = (_Float16)f;
  return __builtin_bit_cast(unsigned short, h);
}

// Exact fp32 distance, bit-identical to the original formula (4-chain fma, then
// fma(-2,dot,fn2)+en2). Packed-key atomicMin: ties -> smaller idx = first occurrence.
static __device__ __forceinline__ void evalExact(const float* __restrict__ inputs,
                                                 const float* __restrict__ embedT,
                                                 const float* __restrict__ en2,
                                                 const float* s_fn2,
                                                 int p0blk, int pl, int c,
                                                 unsigned long long* s_best) {
  int p = p0blk + pl;
  const float* f = inputs + (size_t)p * D;
  const float* e = embedT + (size_t)c * D;
  float a0 = 0.f, a1 = 0.f, a2 = 0.f, a3 = 0.f;
#pragma unroll
  for (int d = 0; d < D; d += 4) {
    a0 = fmaf(f[d + 0], e[d + 0], a0);
    a1 = fmaf(f[d + 1], e[d + 1], a1);
    a2 = fmaf(f[d + 2], e[d + 2], a2);
    a3 = fmaf(f[d + 3], e[d + 3], a3);
  }
  float dot = (a0 + a1) + (a2 + a3);
  float dist = fmaf(-2.f, dot, s_fn2[pl]) + en2[c];
  unsigned long long key = ((unsigned long long)__float_as_uint(dist) << 32) | (unsigned)c;
  atomicMin(&s_best[pl], key);
}

// Merged prep. Blocks 0..3: embed [64][1024] -> embedT fp32 [1024][64],
// embedTh fp16 [1024][64], en2[k] (sequential-fma order), en2max (atomicMax
// on bits; ws poison is a negative int so any positive value wins).
// Blocks 4..515: fn2[p] (original float4 sequential-fma order -> bit-identical),
// best[p] = ~0ull init, done[ptile] = 0 (poison-clear for the fused finalize).
__global__ void __launch_bounds__(256) vq_prep(const float* __restrict__ embed,
                                               const float* __restrict__ inputs,
                                               float* __restrict__ embedT,
                                               unsigned short* __restrict__ embedTh,
                                               float* __restrict__ en2,
                                               int* __restrict__ en2max_bits,
                                               float* __restrict__ fn2,
                                               unsigned long long* __restrict__ best,
                                               int* __restrict__ done) {
  const int bid = blockIdx.x;
  const int tid = threadIdx.x;
  if (bid < KCODES / 256) {
    int k = bid * 256 + tid;
    float row[D];
    float s = 0.f;
#pragma unroll
    for (int d = 0; d < D; ++d) {
      float e = embed[d * KCODES + k];   // coalesced along k
      row[d] = e;
      s = fmaf(e, e, s);
    }
    en2[k] = s;
    float4* o4 = reinterpret_cast<float4*>(embedT + (size_t)k * D);
#pragma unroll
    for (int j = 0; j < 16; ++j)
      o4[j] = make_float4(row[4 * j], row[4 * j + 1], row[4 * j + 2], row[4 * j + 3]);
    unsigned us[32];
#pragma unroll
    for (int j = 0; j < 32; ++j) {
      unsigned lo = f2h(row[2 * j]);
      unsigned hi = f2h(row[2 * j + 1]);
      us[j] = lo | (hi << 16);
    }
    uint4* ob = reinterpret_cast<uint4*>(embedTh + (size_t)k * D);
#pragma unroll
    for (int j = 0; j < 8; ++j)
      ob[j] = make_uint4(us[4 * j], us[4 * j + 1], us[4 * j + 2], us[4 * j + 3]);
    float m = s;
#pragma unroll
    for (int off = 32; off; off >>= 1) m = fmaxf(m, __shfl_down(m, off, 64));
    if ((tid & 63) == 0) atomicMax(en2max_bits, __float_as_int(m));
  } else {
    int p = (bid - KCODES / 256) * 256 + tid;
    const float4* i4 = reinterpret_cast<const float4*>(inputs + (size_t)p * D);
    float s = 0.f;
#pragma unroll
    for (int j = 0; j < 16; ++j) {
      float4 v = i4[j];
      s = fmaf(v.x, v.x, s); s = fmaf(v.y, v.y, s);
      s = fmaf(v.z, v.z, s); s = fmaf(v.w, v.w, s);
    }
    fn2[p] = s;
    best[p] = ~0ull;
    if (tid == 0) done[bid - KCODES / 256] = 0;   // one ptile per fn2-block
  }
}

// K1 (partial+finalize): block = (code-chunk, point-tile); 256 points x 256 codes.
// R6 changes:
//  - structure reverted to R4's proven block-screen loop (R5's wave-local screen
//    overflowed WL_CAP -> 500MB of unfiltered scattered evals)
//  - XCD-aware bid mapping: the 4 chunk-blocks of a ptile share bid%8 -> same
//    XCD L2 -> the ptile's A-tiles fetched from HBM ~once instead of 4x
//  - finalize FUSED: last chunk-block to merge (per-ptile done counter) gathers
//    winners and writes all outputs inline; separate vq_finalize deleted.
__global__ void __launch_bounds__(256, 4) vq_partial(
    const float* __restrict__ inputs, const float* __restrict__ embedT,
    const unsigned short* __restrict__ embedTh, const float* __restrict__ en2,
    const float* __restrict__ fn2, const int* __restrict__ en2max_bits,
    unsigned long long* __restrict__ best, int* __restrict__ done,
    float* __restrict__ out_q, float* __restrict__ out_codes,
    float* __restrict__ out_idx) {
  __shared__ unsigned long long s_best[PTS_PER_BLK];
  __shared__ unsigned s_wl[WL_CAP];
  __shared__ int s_wcount;
  __shared__ float s_fn2[PTS_PER_BLK];
  __shared__ float s_wmin[2][4][16];
  __shared__ int s_last;

  const int tid = threadIdx.x;
  const int w = tid >> 6;
  const int l = tid & 63;
  const int l15 = l & 15;
  const int lg = l >> 4;                 // quad-group 0..3
  // XCD swizzle: ptile,chunk -> bid = (ptile/8)*32 + chunk*8 + ptile%8, so all
  // 4 chunks of a ptile have the same bid%8 (assumed XCD round-robin).
  const int bid = blockIdx.x;
  const int ptile = (bid >> 5) * 8 + (bid & 7);
  const int chunk = (bid >> 3) & 3;
  const int p0blk = ptile * PTS_PER_BLK;
  const int cb = chunk * 256 + w * 64;   // this wave's first code

  s_best[tid] = ~0ull;
  if (tid == 0) s_wcount = 0;
  s_fn2[tid] = fn2[p0blk + tid];

  const float en2max = __int_as_float(*en2max_bits);

  // B fragments: B[k][n], lane holds n = cb+16t+l15, k = kf*32 + lg*8 + j.
  f16x8 bfr[NT][2];
  float en2v[NT];
#pragma unroll
  for (int t = 0; t < NT; ++t) {
    const f16x8* bp = reinterpret_cast<const f16x8*>(
        embedTh + (size_t)(cb + 16 * t + l15) * D + lg * 8);
    bfr[t][0] = bp[0];   // k in [lg*8, lg*8+8)
    bfr[t][1] = bp[4];   // +32 halves -> k in [32+lg*8, ...)
    en2v[t] = en2[cb + 16 * t + l15];
  }

  __syncthreads();  // s_best / s_wcount / s_fn2 ready

#pragma unroll 1
  for (int mt = 0; mt < MTILES; ++mt) {
    const int p0 = p0blk + mt * 16;
    // A fragment: lane holds m = p0+l15, k = kf*32 + lg*8 + j (fp32->fp16 RNE cast).
    const float* arow = inputs + (size_t)(p0 + l15) * D + lg * 8;
    float4 a0 = *reinterpret_cast<const float4*>(arow + 0);
    float4 a1 = *reinterpret_cast<const float4*>(arow + 4);
    float4 a2 = *reinterpret_cast<const float4*>(arow + 32);
    float4 a3 = *reinterpret_cast<const float4*>(arow + 36);
    f16x8 af0, af1;
    af0[0] = (_Float16)a0.x; af0[1] = (_Float16)a0.y; af0[2] = (_Float16)a0.z; af0[3] = (_Float16)a0.w;
    af0[4] = (_Float16)a1.x; af0[5] = (_Float16)a1.y; af0[6] = (_Float16)a1.z; af0[7] = (_Float16)a1.w;
    af1[0] = (_Float16)a2.x; af1[1] = (_Float16)a2.y; af1[2] = (_Float16)a2.z; af1[3] = (_Float16)a2.w;
    af1[4] = (_Float16)a3.x; af1[5] = (_Float16)a3.y; af1[6] = (_Float16)a3.z; af1[7] = (_Float16)a3.w;

    f32x4 acc[NT];
#pragma unroll
    for (int t = 0; t < NT; ++t) acc[t] = (f32x4){0.f, 0.f, 0.f, 0.f};
#pragma unroll
    for (int t = 0; t < NT; ++t)
      acc[t] = __builtin_amdgcn_mfma_f32_16x16x32_f16(af0, bfr[t][0], acc[t], 0, 0, 0);
#pragma unroll
    for (int t = 0; t < NT; ++t)
      acc[t] = __builtin_amdgcn_mfma_f32_16x16x32_f16(af1, bfr[t][1], acc[t], 0, 0, 0);

    // C/D layout: row(point) = lg*4 + reg, col(code) = l15 [m89/m91-verified].
    // Screened quantity d' = en2 - 2*dot (per-point fn2 constant dropped).
#pragma unroll
    for (int t = 0; t < NT; ++t)
#pragma unroll
      for (int r = 0; r < 4; ++r)
        acc[t][r] = fmaf(-2.f, acc[t][r], en2v[t]);

    // Block-global screening min over this block's 256 codes (tight worklist):
    // lane-local over t, butterfly over 16 cols, LDS exchange over 4 waves.
    float m[4];
#pragma unroll
    for (int r = 0; r < 4; ++r) {
      float mm = acc[0][r];
#pragma unroll
      for (int t = 1; t < NT; ++t) mm = fminf(mm, acc[t][r]);
#pragma unroll
      for (int s = 1; s < 16; s <<= 1) mm = fminf(mm, __shfl_xor(mm, s, 16));
      m[r] = mm;
    }
    if (l15 == 0) {
#pragma unroll
      for (int r = 0; r < 4; ++r) s_wmin[mt & 1][w][lg * 4 + r] = m[r];
    }
    __syncthreads();  // single barrier: next tile uses the other buffer
    float fnv[4];
#pragma unroll
    for (int r = 0; r < 4; ++r) fnv[r] = s_fn2[mt * 16 + lg * 4 + r];
    float thr[4];
#pragma unroll
    for (int r = 0; r < 4; ++r) {
      int q = lg * 4 + r;
      float fm = fminf(fminf(s_wmin[mt & 1][0][q], s_wmin[mt & 1][1][q]),
                       fminf(s_wmin[mt & 1][2][q], s_wmin[mt & 1][3][q]));
      // margin >= 2*|d'~ - d'|: fp16 u=2^-11, products exact in fp32 ->
      // |err| <= 4u*sqrt(fn2*en2max) = 2^-9*sqrt(...); x2 safety -> 2^-8.
      // + 0.01 slack for fp32 accumulation-order differences.
      thr[r] = fm + (0.00390625f * sqrtf(fnv[r] * en2max) + 0.01f);
    }
#pragma unroll
    for (int t = 0; t < NT; ++t)
#pragma unroll
      for (int r = 0; r < 4; ++r)
        if (acc[t][r] <= thr[r]) {
          int pl = mt * 16 + lg * 4 + r;
          int c = cb + 16 * t + l15;
          int pos = atomicAdd(&s_wcount, 1);
          if (pos < WL_CAP) s_wl[pos] = (unsigned)((pl << 10) | c);
          else evalExact(inputs, embedT, en2, s_fn2, p0blk, pl, c, s_best);  // overflow
        }
  }

  __syncthreads();  // worklist complete

  // Exact re-eval of the worklist (parallel across the block).
  int wc = s_wcount; if (wc > WL_CAP) wc = WL_CAP;
  for (int i = tid; i < wc; i += 256)
    evalExact(inputs, embedT, en2, s_fn2, p0blk, (int)(s_wl[i] >> 10), (int)(s_wl[i] & 1023), s_best);
  __syncthreads();

  // Merge this chunk's result into the global per-point best.
  atomicMin(&best[p0blk + tid], s_best[tid]);
  __threadfence();      // make this thread's merge globally visible
  __syncthreads();      // all 256 merges + fences done
  if (tid == 0) s_last = (atomicAdd(&done[ptile], 1) == CODE_CHUNKS - 1);
  __syncthreads();

  // Fused finalize: exactly one of the 4 chunk-blocks sees s_last. Its 3 peers'
  // merges are visible (their fence precedes their done-increment; our read of
  // done==3 is after). best[] read via no-op atomicMin = device-scope load.
  if (s_last) {
    const int sub = tid & 3;
#pragma unroll 1
    for (int pass = 0; pass < 4; ++pass) {
      int pl = pass * 64 + (tid >> 2);
      int p = p0blk + pl;
      unsigned long long key = atomicMin(&best[p], ~0ull);  // read, never writes
      int c = (int)(unsigned)(key & 0xFFFFFFFFu);
      const f32x4* qrow = reinterpret_cast<const f32x4*>(embedT + (size_t)c * D);
      const f32x4* frow = reinterpret_cast<const f32x4*>(inputs + (size_t)p * D);
      f32x4* oq = reinterpret_cast<f32x4*>(out_q + (size_t)p * D);
      f32x4* oc = reinterpret_cast<f32x4*>(out_codes + (size_t)p * 2 * D);
#pragma unroll
      for (int j = 0; j < 4; ++j) {
        int i4 = j * 4 + sub;
        f32x4 qv = qrow[i4];
        f32x4 fv = frow[i4];
        oq[i4] = qv;
        oc[i4] = fv;
        oc[16 + i4] = qv;
      }
      if (sub == 0) out_idx[p] = (float)c;
    }
  }
}

extern "C" void kernel_launch(void* const* d_in, const int* in_sizes, int n_in,
                              void* d_out, int out_size, void* d_ws, size_t ws_size,
                              hipStream_t stream) {
  const float* inputs = (const float*)d_in[0];
  const float* embed  = (const float*)d_in[1];
  int N = in_sizes[0] / D;  // 131072

  // ws layout (~1.9 MB): best first for 8B alignment.
  unsigned long long* best  = (unsigned long long*)d_ws;              // 1 MB
  float* embedT             = (float*)(best + N);                     // 256 KB
  unsigned short* embedTh   = (unsigned short*)(embedT + KCODES * D); // 128 KB (fp16)
  float* en2                = (float*)(embedTh + KCODES * D);         // 4 KB
  float* fn2                = en2 + KCODES;                           // 512 KB
  int* en2max_bits          = (int*)(fn2 + N);                        // 4 B
  int* done                 = en2max_bits + 1;                        // 2 KB (PTILES ints)

  float* out = (float*)d_out;
  float* out_q     = out;                      // [N, 64]
  float* out_codes = out + (size_t)N * D;      // [N, 128]
  float* out_idx   = out + (size_t)N * D * 3;  // [N]

  vq_prep<<<KCODES / 256 + N / 256, 256, 0, stream>>>(embed, inputs, embedT, embedTh,
                                                      en2, en2max_bits, fn2, best, done);
  vq_partial<<<CODE_CHUNKS * PTILES, 256, 0, stream>>>(inputs, embedT, embedTh, en2,
                                                       fn2, en2max_bits, best, done,
                                                       out_q, out_codes, out_idx);
}

// Round 7
// 311.477 us; speedup vs baseline: 1.6839x; 1.6839x over previous
//
#include <hip/hip_runtime.h>

#define D 64
#define KCODES 1024
#define PTS_PER_BLK 256
#define MTILES 16        // 16 points per M-tile x 16 tiles = 256 points/block
#define NT 4             // 4 N-tiles of 16 codes per wave = 64 codes/wave, 256/block
#define CODE_CHUNKS 4    // 4 blocks cover the 1024 codes for one point-tile
#define PTILES 512       // N / PTS_PER_BLK
#define WL_CAP 2048

typedef _Float16 f16x8 __attribute__((ext_vector_type(8)));
typedef float f32x4 __attribute__((ext_vector_type(4)));

static __device__ __forceinline__ unsigned short f2h(float f) {  // RNE fp32->fp16
  _Float16 h = (_Float16)f;
  return __builtin_bit_cast(unsigned short, h);
}

// Exact fp32 distance (4-chain fma, then fma(-2,dot,fn2)+en2). Packed-key
// atomicMin: ties -> smaller idx = first occurrence.
static __device__ __forceinline__ void evalExact(const float* __restrict__ inputs,
                                                 const float* __restrict__ embedT,
                                                 const float* __restrict__ en2,
                                                 const float* s_fn2,
                                                 int p0blk, int pl, int c,
                                                 unsigned long long* s_best) {
  int p = p0blk + pl;
  const float* f = inputs + (size_t)p * D;
  const float* e = embedT + (size_t)c * D;
  float a0 = 0.f, a1 = 0.f, a2 = 0.f, a3 = 0.f;
#pragma unroll
  for (int d = 0; d < D; d += 4) {
    a0 = fmaf(f[d + 0], e[d + 0], a0);
    a1 = fmaf(f[d + 1], e[d + 1], a1);
    a2 = fmaf(f[d + 2], e[d + 2], a2);
    a3 = fmaf(f[d + 3], e[d + 3], a3);
  }
  float dot = (a0 + a1) + (a2 + a3);
  float dist = fmaf(-2.f, dot, s_fn2[pl]) + en2[c];
  unsigned long long key = ((unsigned long long)__float_as_uint(dist) << 32) | (unsigned)c;
  atomicMin(&s_best[pl], key);
}

// Merged prep. Blocks 0..3: embed [64][1024] -> embedT fp32 [1024][64],
// embedTh fp16 [1024][64], en2[k], en2max (atomicMax on bits).
// Blocks 4..515: fn2[p] (per-thread sequential-fma, consistent with evalExact),
// best[p] = ~0ull init, and the out_codes INPUTS-HALF via a coalesced 4-lane
// copy (R2 proved the fusion correct; this fixes its write pattern).
__global__ void __launch_bounds__(256) vq_prep(const float* __restrict__ embed,
                                               const float* __restrict__ inputs,
                                               float* __restrict__ embedT,
                                               unsigned short* __restrict__ embedTh,
                                               float* __restrict__ en2,
                                               int* __restrict__ en2max_bits,
                                               float* __restrict__ fn2,
                                               unsigned long long* __restrict__ best,
                                               float* __restrict__ out_codes) {
  const int bid = blockIdx.x;
  const int tid = threadIdx.x;
  if (bid < KCODES / 256) {
    int k = bid * 256 + tid;
    float row[D];
    float s = 0.f;
#pragma unroll
    for (int d = 0; d < D; ++d) {
      float e = embed[d * KCODES + k];   // coalesced along k
      row[d] = e;
      s = fmaf(e, e, s);
    }
    en2[k] = s;
    float4* o4 = reinterpret_cast<float4*>(embedT + (size_t)k * D);
#pragma unroll
    for (int j = 0; j < 16; ++j)
      o4[j] = make_float4(row[4 * j], row[4 * j + 1], row[4 * j + 2], row[4 * j + 3]);
    unsigned us[32];
#pragma unroll
    for (int j = 0; j < 32; ++j) {
      unsigned lo = f2h(row[2 * j]);
      unsigned hi = f2h(row[2 * j + 1]);
      us[j] = lo | (hi << 16);
    }
    uint4* ob = reinterpret_cast<uint4*>(embedTh + (size_t)k * D);
#pragma unroll
    for (int j = 0; j < 8; ++j)
      ob[j] = make_uint4(us[4 * j], us[4 * j + 1], us[4 * j + 2], us[4 * j + 3]);
    float m = s;
#pragma unroll
    for (int off = 32; off; off >>= 1) m = fmaxf(m, __shfl_down(m, off, 64));
    if ((tid & 63) == 0) atomicMax(en2max_bits, __float_as_int(m));
  } else {
    const int p0blk = (bid - KCODES / 256) * 256;
    int p = p0blk + tid;
    const float4* i4 = reinterpret_cast<const float4*>(inputs + (size_t)p * D);
    float s = 0.f;
#pragma unroll
    for (int j = 0; j < 16; ++j) {
      float4 v = i4[j];
      s = fmaf(v.x, v.x, s); s = fmaf(v.y, v.y, s);
      s = fmaf(v.z, v.z, s); s = fmaf(v.w, v.w, s);
    }
    fn2[p] = s;
    best[p] = ~0ull;
    // Coalesced inputs -> out_codes[ :64] copy (4 lanes cooperate per point;
    // inputs rows are L2-hot from the fn2 pass above).
    const int sub = tid & 3;
#pragma unroll 1
    for (int pass = 0; pass < 4; ++pass) {
      int pl = pass * 64 + (tid >> 2);
      int pp = p0blk + pl;
      const f32x4* frow = reinterpret_cast<const f32x4*>(inputs + (size_t)pp * D);
      f32x4* oc = reinterpret_cast<f32x4*>(out_codes + (size_t)pp * 2 * D);
#pragma unroll
      for (int j = 0; j < 4; ++j) {
        int i4x = j * 4 + sub;
        oc[i4x] = frow[i4x];
      }
    }
  }
}

// K1 (partial): block = (code-chunk, point-tile); 256 points x 256 codes.
// R7: R4's proven block-screen loop, unchanged, PLUS the XCD-aware bid mapping
// verified by R6's FETCH counter (100->54 MB): the 4 chunk-blocks of a ptile
// share bid%8 -> same XCD L2 -> the ptile's A-tiles fetched from HBM ~once.
// R6's fused finalize / done counter / threadfence are REVERTED (they doubled
// duration via device-scope fences + serialized tails).
__global__ void __launch_bounds__(256, 4) vq_partial(
    const float* __restrict__ inputs, const float* __restrict__ embedT,
    const unsigned short* __restrict__ embedTh, const float* __restrict__ en2,
    const float* __restrict__ fn2, const int* __restrict__ en2max_bits,
    unsigned long long* __restrict__ best) {
  __shared__ unsigned long long s_best[PTS_PER_BLK];
  __shared__ unsigned s_wl[WL_CAP];
  __shared__ int s_wcount;
  __shared__ float s_fn2[PTS_PER_BLK];
  __shared__ float s_wmin[2][4][16];

  const int tid = threadIdx.x;
  const int w = tid >> 6;
  const int l = tid & 63;
  const int l15 = l & 15;
  const int lg = l >> 4;                 // quad-group 0..3
  // XCD swizzle: bid = (ptile/8)*32 + chunk*8 + ptile%8 (bijective, PTILES%8==0).
  const int bid = blockIdx.x;
  const int ptile = (bid >> 5) * 8 + (bid & 7);
  const int chunk = (bid >> 3) & 3;
  const int p0blk = ptile * PTS_PER_BLK;
  const int cb = chunk * 256 + w * 64;   // this wave's first code

  s_best[tid] = ~0ull;
  if (tid == 0) s_wcount = 0;
  s_fn2[tid] = fn2[p0blk + tid];

  const float en2max = __int_as_float(*en2max_bits);

  // B fragments: B[k][n], lane holds n = cb+16t+l15, k = kf*32 + lg*8 + j.
  f16x8 bfr[NT][2];
  float en2v[NT];
#pragma unroll
  for (int t = 0; t < NT; ++t) {
    const f16x8* bp = reinterpret_cast<const f16x8*>(
        embedTh + (size_t)(cb + 16 * t + l15) * D + lg * 8);
    bfr[t][0] = bp[0];   // k in [lg*8, lg*8+8)
    bfr[t][1] = bp[4];   // +32 halves -> k in [32+lg*8, ...)
    en2v[t] = en2[cb + 16 * t + l15];
  }

  __syncthreads();  // s_best / s_wcount / s_fn2 ready

#pragma unroll 1
  for (int mt = 0; mt < MTILES; ++mt) {
    const int p0 = p0blk + mt * 16;
    // A fragment: lane holds m = p0+l15, k = kf*32 + lg*8 + j (fp32->fp16 RNE cast).
    const float* arow = inputs + (size_t)(p0 + l15) * D + lg * 8;
    float4 a0 = *reinterpret_cast<const float4*>(arow + 0);
    float4 a1 = *reinterpret_cast<const float4*>(arow + 4);
    float4 a2 = *reinterpret_cast<const float4*>(arow + 32);
    float4 a3 = *reinterpret_cast<const float4*>(arow + 36);
    f16x8 af0, af1;
    af0[0] = (_Float16)a0.x; af0[1] = (_Float16)a0.y; af0[2] = (_Float16)a0.z; af0[3] = (_Float16)a0.w;
    af0[4] = (_Float16)a1.x; af0[5] = (_Float16)a1.y; af0[6] = (_Float16)a1.z; af0[7] = (_Float16)a1.w;
    af1[0] = (_Float16)a2.x; af1[1] = (_Float16)a2.y; af1[2] = (_Float16)a2.z; af1[3] = (_Float16)a2.w;
    af1[4] = (_Float16)a3.x; af1[5] = (_Float16)a3.y; af1[6] = (_Float16)a3.z; af1[7] = (_Float16)a3.w;

    f32x4 acc[NT];
#pragma unroll
    for (int t = 0; t < NT; ++t) acc[t] = (f32x4){0.f, 0.f, 0.f, 0.f};
#pragma unroll
    for (int t = 0; t < NT; ++t)
      acc[t] = __builtin_amdgcn_mfma_f32_16x16x32_f16(af0, bfr[t][0], acc[t], 0, 0, 0);
#pragma unroll
    for (int t = 0; t < NT; ++t)
      acc[t] = __builtin_amdgcn_mfma_f32_16x16x32_f16(af1, bfr[t][1], acc[t], 0, 0, 0);

    // C/D layout: row(point) = lg*4 + reg, col(code) = l15 [m89/m91-verified].
    // Screened quantity d' = en2 - 2*dot (per-point fn2 constant dropped).
#pragma unroll
    for (int t = 0; t < NT; ++t)
#pragma unroll
      for (int r = 0; r < 4; ++r)
        acc[t][r] = fmaf(-2.f, acc[t][r], en2v[t]);

    // Block-global screening min over this block's 256 codes (tight worklist):
    // lane-local over t, butterfly over 16 cols, LDS exchange over 4 waves.
    float m[4];
#pragma unroll
    for (int r = 0; r < 4; ++r) {
      float mm = acc[0][r];
#pragma unroll
      for (int t = 1; t < NT; ++t) mm = fminf(mm, acc[t][r]);
#pragma unroll
      for (int s = 1; s < 16; s <<= 1) mm = fminf(mm, __shfl_xor(mm, s, 16));
      m[r] = mm;
    }
    if (l15 == 0) {
#pragma unroll
      for (int r = 0; r < 4; ++r) s_wmin[mt & 1][w][lg * 4 + r] = m[r];
    }
    __syncthreads();  // single barrier: next tile uses the other buffer
    float fnv[4];
#pragma unroll
    for (int r = 0; r < 4; ++r) fnv[r] = s_fn2[mt * 16 + lg * 4 + r];
    float thr[4];
#pragma unroll
    for (int r = 0; r < 4; ++r) {
      int q = lg * 4 + r;
      float fm = fminf(fminf(s_wmin[mt & 1][0][q], s_wmin[mt & 1][1][q]),
                       fminf(s_wmin[mt & 1][2][q], s_wmin[mt & 1][3][q]));
      // margin >= 2*|d'~ - d'|: fp16 u=2^-11, products exact in fp32 ->
      // |err| <= 4u*sqrt(fn2*en2max) = 2^-9*sqrt(...); x2 safety -> 2^-8.
      // + 0.01 slack for fp32 accumulation-order differences.
      thr[r] = fm + (0.00390625f * sqrtf(fnv[r] * en2max) + 0.01f);
    }
#pragma unroll
    for (int t = 0; t < NT; ++t)
#pragma unroll
      for (int r = 0; r < 4; ++r)
        if (acc[t][r] <= thr[r]) {
          int pl = mt * 16 + lg * 4 + r;
          int c = cb + 16 * t + l15;
          int pos = atomicAdd(&s_wcount, 1);
          if (pos < WL_CAP) s_wl[pos] = (unsigned)((pl << 10) | c);
          else evalExact(inputs, embedT, en2, s_fn2, p0blk, pl, c, s_best);  // overflow
        }
  }

  __syncthreads();  // worklist complete

  // Exact re-eval of the worklist (parallel across the block).
  int wc = s_wcount; if (wc > WL_CAP) wc = WL_CAP;
  for (int i = tid; i < wc; i += 256)
    evalExact(inputs, embedT, en2, s_fn2, p0blk, (int)(s_wl[i] >> 10), (int)(s_wl[i] & 1023), s_best);
  __syncthreads();

  // Merge this chunk's result into the global per-point best.
  atomicMin(&best[p0blk + tid], s_best[tid]);
}

// K2 (finalize): stream points; gather the winning code row; write the
// quantized outputs (inputs-half of out_codes was already written by prep).
__global__ void __launch_bounds__(256) vq_finalize(
    const float* __restrict__ embedT,
    const unsigned long long* __restrict__ best,
    float* __restrict__ out_q, float* __restrict__ out_codes,
    float* __restrict__ out_idx) {
  const int tid = threadIdx.x;
  const int p0blk = blockIdx.x * 256;
  const int sub = tid & 3;
#pragma unroll 1
  for (int pass = 0; pass < 4; ++pass) {
    int pl = pass * 64 + (tid >> 2);
    int p = p0blk + pl;
    unsigned long long key = best[p];
    int c = (int)(unsigned)(key & 0xFFFFFFFFu);
    const f32x4* qrow = reinterpret_cast<const f32x4*>(embedT + (size_t)c * D);
    f32x4* oq = reinterpret_cast<f32x4*>(out_q + (size_t)p * D);
    f32x4* oc = reinterpret_cast<f32x4*>(out_codes + (size_t)p * 2 * D);
#pragma unroll
    for (int j = 0; j < 4; ++j) {
      int i4 = j * 4 + sub;
      f32x4 qv = qrow[i4];
      oq[i4] = qv;
      oc[16 + i4] = qv;
    }
    if (sub == 0) out_idx[p] = (float)c;
  }
}

extern "C" void kernel_launch(void* const* d_in, const int* in_sizes, int n_in,
                              void* d_out, int out_size, void* d_ws, size_t ws_size,
                              hipStream_t stream) {
  const float* inputs = (const float*)d_in[0];
  const float* embed  = (const float*)d_in[1];
  int N = in_sizes[0] / D;  // 131072

  // ws layout (~1.9 MB): best first for 8B alignment.
  unsigned long long* best  = (unsigned long long*)d_ws;              // 1 MB
  float* embedT             = (float*)(best + N);                     // 256 KB
  unsigned short* embedTh   = (unsigned short*)(embedT + KCODES * D); // 128 KB (fp16)
  float* en2                = (float*)(embedTh + KCODES * D);         // 4 KB
  float* fn2                = en2 + KCODES;                           // 512 KB
  int* en2max_bits          = (int*)(fn2 + N);                        // 4 B

  float* out = (float*)d_out;
  float* out_q     = out;                      // [N, 64]
  float* out_codes = out + (size_t)N * D;      // [N, 128]
  float* out_idx   = out + (size_t)N * D * 3;  // [N]

  vq_prep<<<KCODES / 256 + N / 256, 256, 0, stream>>>(embed, inputs, embedT, embedTh,
                                                      en2, en2max_bits, fn2, best, out_codes);
  vq_partial<<<CODE_CHUNKS * PTILES, 256, 0, stream>>>(inputs, embedT, embedTh, en2,
                                                       fn2, en2max_bits, best);
  vq_finalize<<<N / 256, 256, 0, stream>>>(embedT, best, out_q, out_codes, out_idx);
}